// Round 1
// baseline (604.618 us; speedup 1.0000x reference)
//
#include <hip/hip_runtime.h>
#include <stdint.h>

// Problem constants (fixed by setup_inputs)
#define NB 32
#define NC 128
#define NH 56
#define NW 56
#define NHW_ (NH * NW)      // 3136
#define NPIX (NB * NHW_)    // 100352
#define NO 128
#define NK 1152             // NC * 9

typedef unsigned long long u64;

// ---------------------------------------------------------------------------
// K1: sign(x + bias0) packed into 128-bit-per-pixel bitplanes.
// bit c of word j (c = j*64 + cc) is 1 iff (x[n,c,h,w] + bias0[c]) > 0.
// ---------------------------------------------------------------------------
__global__ __launch_bounds__(256) void pack_act(const float* __restrict__ x,
                                                const float* __restrict__ bias0,
                                                u64* __restrict__ packA) {
    int p = blockIdx.x * 256 + threadIdx.x;  // pixel index n*HW + h*W + w
    if (p >= NPIX) return;
    int n = p / NHW_;
    int rem = p - n * NHW_;
    const float* xb = x + (size_t)n * NC * NHW_ + rem;
    u64 w0 = 0, w1 = 0;
#pragma unroll 8
    for (int c = 0; c < 64; ++c)
        w0 |= (u64)((xb[(size_t)c * NHW_] + bias0[c]) > 0.f) << c;
#pragma unroll 8
    for (int c = 0; c < 64; ++c)
        w1 |= (u64)((xb[(size_t)(c + 64) * NHW_] + bias0[c + 64]) > 0.f) << c;
    packA[(size_t)p * 2]     = w0;
    packA[(size_t)p * 2 + 1] = w1;
}

// ---------------------------------------------------------------------------
// K2: per-output-channel weight scale (mean |w|) + sign bitplanes.
// packW[o][tap][j], tap = kh*3+kw, bit cc covers c = j*64+cc.
// ---------------------------------------------------------------------------
__global__ __launch_bounds__(64) void pack_wgt(const float* __restrict__ w,
                                               u64* __restrict__ packW,
                                               float* __restrict__ scaleW) {
    int o = blockIdx.x;
    int t = threadIdx.x;  // 64 threads
    const float* wo = w + (size_t)o * NK;
    float s = 0.f;
    for (int i = t; i < NK; i += 64) s += fabsf(wo[i]);
    for (int off = 32; off; off >>= 1) s += __shfl_down(s, off);
    if (t == 0) scaleW[o] = s / (float)NK;
    if (t < 18) {
        int tap = t >> 1;
        int j   = t & 1;
        u64 bits = 0;
        for (int cc = 0; cc < 64; ++cc) {
            int c = j * 64 + cc;
            bits |= (u64)(wo[c * 9 + tap] > 0.f) << cc;
        }
        packW[((size_t)o * 9 + tap) * 2 + j] = bits;
    }
}

// ---------------------------------------------------------------------------
// Load the 3x3 packed neighborhood for pixel (n, h, wcol). Border taps are
// flagged invalid (contribute 0 = zero-padding of binarized input).
// ---------------------------------------------------------------------------
__device__ inline void load_nbhd(const u64* __restrict__ packA, int n, int h,
                                 int wcol, bool act, u64 a[9][2], unsigned* vmask) {
    unsigned m = 0;
#pragma unroll
    for (int kh = 0; kh < 3; ++kh) {
        int hi = h + kh - 1;
        bool vh = (hi >= 0) && (hi < NH);
#pragma unroll
        for (int kw = 0; kw < 3; ++kw) {
            int wi = wcol + kw - 1;
            int t = kh * 3 + kw;
            bool v = act && vh && (wi >= 0) && (wi < NW);
            // clamp so the (exec-masked-out anyway) address is in-bounds
            int hc = hi < 0 ? 0 : (hi >= NH ? NH - 1 : hi);
            int wc = wi < 0 ? 0 : (wi >= NW ? NW - 1 : wi);
            size_t idx = ((size_t)n * NHW_ + (size_t)hc * NW + wc) * 2;
            u64 q0 = packA[idx], q1 = packA[idx + 1];
            a[t][0] = v ? q0 : 0;
            a[t][1] = v ? q1 : 0;
            m |= (unsigned)v << t;
        }
    }
    *vmask = m;
}

// ---------------------------------------------------------------------------
// K3: binary conv via XOR+popcount. One block per (n, h) row; 4 waves, each
// wave handles 32 output channels for the 56 pixels of the row (lanes 0..55).
// Accumulates exact integer per-channel sum / sumsq for BatchNorm stats.
// STORE: also writes int16 conv outputs to yI.
// ---------------------------------------------------------------------------
template <bool STORE>
__global__ __launch_bounds__(256) void conv_stats(const u64* __restrict__ packA,
                                                  const u64* __restrict__ packW,
                                                  int* __restrict__ sumI,
                                                  u64* __restrict__ sumsqI,
                                                  short* __restrict__ yI) {
    __shared__ u64 lw[NO * 9 * 2];  // 18 KB
    for (int i = threadIdx.x; i < NO * 9 * 2; i += 256) lw[i] = packW[i];

    int nh = blockIdx.x;
    int n = nh / NH, h = nh - n * NH;
    int wave = threadIdx.x >> 6, lane = threadIdx.x & 63;
    bool act = lane < NW;

    u64 a[9][2];
    unsigned vm;
    load_nbhd(packA, n, h, lane, act, a, &vm);
    __syncthreads();

    for (int oo = 0; oo < 32; ++oo) {
        int o = (wave << 5) + oo;
        int dot = 0;
#pragma unroll
        for (int t = 0; t < 9; ++t) {
            int pc = __popcll(a[t][0] ^ lw[((size_t)o * 9 + t) * 2]) +
                     __popcll(a[t][1] ^ lw[((size_t)o * 9 + t) * 2 + 1]);
            dot += ((vm >> t) & 1) ? (NC - 2 * pc) : 0;
        }
        // inactive lanes have vm==0 -> dot==0, safe to include in reduction
        if (STORE && act)
            yI[((size_t)n * NO + o) * NHW_ + (size_t)h * NW + lane] = (short)dot;
        int s = dot;
        int sq = dot * dot;  // row-sumsq <= 56*1152^2 = 7.4e7, fits int32
        for (int off = 32; off; off >>= 1) {
            s  += __shfl_down(s, off);
            sq += __shfl_down(sq, off);
        }
        if (lane == 0) {
            atomicAdd(&sumI[o], s);
            atomicAdd(&sumsqI[o], (u64)(unsigned)sq);
        }
    }
}

// ---------------------------------------------------------------------------
// K4: fold weight scale + BN(mean,var,gamma,beta) + bias1 into per-channel
// affine: y_pre_prelu = coefA[o]*dot + coefB[o] + x
// ---------------------------------------------------------------------------
__global__ __launch_bounds__(128) void bn_coef(const int* __restrict__ sumI,
                                               const u64* __restrict__ sumsqI,
                                               const float* __restrict__ scaleW,
                                               const float* __restrict__ gamma,
                                               const float* __restrict__ beta,
                                               const float* __restrict__ bias1,
                                               float* __restrict__ coefA,
                                               float* __restrict__ coefB) {
    int o = threadIdx.x;
    double cnt = (double)NPIX;
    double mean = (double)sumI[o] / cnt;
    double var = (double)sumsqI[o] / cnt - mean * mean;
    if (var < 0.0) var = 0.0;
    float sc = scaleW[o];
    float rs = rsqrtf((float)((double)sc * (double)sc * var) + 1e-5f);
    float g = gamma[o];
    float a = sc * g * rs;
    float b = beta[o] - (float)((double)sc * mean) * g * rs;
    coefA[o] = a;
    coefB[o] = b + bias1[o];
}

// ---------------------------------------------------------------------------
// K5a (store path): elementwise epilogue, 8 elems/thread vectorized.
// out = prelu(coefA*y + coefB + x) + bias2
// ---------------------------------------------------------------------------
__global__ __launch_bounds__(256) void final_store(const short* __restrict__ yI,
                                                   const float* __restrict__ x,
                                                   const float* __restrict__ coefA,
                                                   const float* __restrict__ coefB,
                                                   const float* __restrict__ alpha,
                                                   const float* __restrict__ bias2,
                                                   float* __restrict__ out) {
    const size_t ngroups = (size_t)NB * NO * NHW_ / 8;  // HW%8==0 -> same o per group
    for (size_t g = (size_t)blockIdx.x * blockDim.x + threadIdx.x; g < ngroups;
         g += (size_t)gridDim.x * blockDim.x) {
        size_t i = g * 8;
        int o = (int)((i / NHW_) % NO);
        float a = coefA[o], bb = coefB[o], al = alpha[o], b2 = bias2[o];
        int4 yv = *reinterpret_cast<const int4*>(yI + i);
        float4 x0 = *reinterpret_cast<const float4*>(x + i);
        float4 x1 = *reinterpret_cast<const float4*>(x + i + 4);
        int q[4] = {yv.x, yv.y, yv.z, yv.w};
        float xs[8] = {x0.x, x0.y, x0.z, x0.w, x1.x, x1.y, x1.z, x1.w};
        float r[8];
#pragma unroll
        for (int j = 0; j < 4; ++j) {
            float lo = (float)(short)(q[j] & 0xffff);
            float hi = (float)(q[j] >> 16);
            float t0 = fmaf(a, lo, bb) + xs[2 * j];
            float t1 = fmaf(a, hi, bb) + xs[2 * j + 1];
            t0 = t0 >= 0.f ? t0 : al * t0;
            t1 = t1 >= 0.f ? t1 : al * t1;
            r[2 * j]     = t0 + b2;
            r[2 * j + 1] = t1 + b2;
        }
        float4 o0 = {r[0], r[1], r[2], r[3]};
        float4 o1 = {r[4], r[5], r[6], r[7]};
        *reinterpret_cast<float4*>(out + i)     = o0;
        *reinterpret_cast<float4*>(out + i + 4) = o1;
    }
}

// ---------------------------------------------------------------------------
// K5b (fallback, tiny-ws path): recompute conv (L2-resident bitplanes) and
// apply epilogue directly.
// ---------------------------------------------------------------------------
__global__ __launch_bounds__(256) void final_recompute(const u64* __restrict__ packA,
                                                       const u64* __restrict__ packW,
                                                       const float* __restrict__ coefA,
                                                       const float* __restrict__ coefB,
                                                       const float* __restrict__ alpha,
                                                       const float* __restrict__ bias2,
                                                       const float* __restrict__ x,
                                                       float* __restrict__ out) {
    __shared__ u64 lw[NO * 9 * 2];
    for (int i = threadIdx.x; i < NO * 9 * 2; i += 256) lw[i] = packW[i];

    int nh = blockIdx.x;
    int n = nh / NH, h = nh - n * NH;
    int wave = threadIdx.x >> 6, lane = threadIdx.x & 63;
    bool act = lane < NW;

    u64 a[9][2];
    unsigned vm;
    load_nbhd(packA, n, h, lane, act, a, &vm);
    __syncthreads();

    for (int oo = 0; oo < 32; ++oo) {
        int o = (wave << 5) + oo;
        int dot = 0;
#pragma unroll
        for (int t = 0; t < 9; ++t) {
            int pc = __popcll(a[t][0] ^ lw[((size_t)o * 9 + t) * 2]) +
                     __popcll(a[t][1] ^ lw[((size_t)o * 9 + t) * 2 + 1]);
            dot += ((vm >> t) & 1) ? (NC - 2 * pc) : 0;
        }
        if (act) {
            size_t idx = ((size_t)n * NO + o) * NHW_ + (size_t)h * NW + lane;
            float t = fmaf(coefA[o], (float)dot, coefB[o]) + x[idx];
            t = t >= 0.f ? t : alpha[o] * t;
            out[idx] = t + bias2[o];
        }
    }
}

// ---------------------------------------------------------------------------
// Workspace layout (bytes):
//   0        packA   (NB*HW*2 u64)   1,605,632
//   1605632  packW   (128*9*2 u64)      18,432
//   1624064  scaleW  (128 f32)             512
//   1624576  sumI    (128 i32)             512   } memset 0 each call
//   1625088  sumsqI  (128 u64)           1,024   }
//   1626112  coefA   (128 f32)             512
//   1626624  coefB   (128 f32)             512
//   1630208  yI      (int16, store path) 25,690,112
// ---------------------------------------------------------------------------
extern "C" void kernel_launch(void* const* d_in, const int* in_sizes, int n_in,
                              void* d_out, int out_size, void* d_ws, size_t ws_size,
                              hipStream_t stream) {
    (void)in_sizes; (void)n_in; (void)out_size;
    const float* x     = (const float*)d_in[0];
    const float* bias0 = (const float*)d_in[1];
    const float* w     = (const float*)d_in[2];
    const float* gamma = (const float*)d_in[3];
    const float* beta  = (const float*)d_in[4];
    const float* bias1 = (const float*)d_in[5];
    const float* alpha = (const float*)d_in[6];
    const float* bias2 = (const float*)d_in[7];
    float* out = (float*)d_out;
    char* ws = (char*)d_ws;

    u64*   packA  = (u64*)ws;
    u64*   packW  = (u64*)(ws + 1605632);
    float* scaleW = (float*)(ws + 1624064);
    int*   sumI   = (int*)(ws + 1624576);
    u64*   sumsqI = (u64*)(ws + 1625088);
    float* coefA  = (float*)(ws + 1626112);
    float* coefB  = (float*)(ws + 1626624);
    short* yI     = (short*)(ws + 1630208);
    bool store = ws_size >= (size_t)1630208 + (size_t)NB * NO * NHW_ * 2;

    hipMemsetAsync(ws + 1624576, 0, 1536, stream);  // zero sumI + sumsqI

    pack_act<<<NPIX / 256, 256, 0, stream>>>(x, bias0, packA);
    pack_wgt<<<NO, 64, 0, stream>>>(w, packW, scaleW);
    if (store)
        conv_stats<true><<<NB * NH, 256, 0, stream>>>(packA, packW, sumI, sumsqI, yI);
    else
        conv_stats<false><<<NB * NH, 256, 0, stream>>>(packA, packW, sumI, sumsqI, nullptr);
    bn_coef<<<1, NO, 0, stream>>>(sumI, sumsqI, scaleW, gamma, beta, bias1, coefA, coefB);
    if (store)
        final_store<<<2048, 256, 0, stream>>>(yI, x, coefA, coefB, alpha, bias2, out);
    else
        final_recompute<<<NB * NH, 256, 0, stream>>>(packA, packW, coefA, coefB, alpha, bias2, x, out);
}

// Round 2
// 105.311 us; speedup vs baseline: 5.7413x; 5.7413x over previous
//
#include <hip/hip_runtime.h>
#include <stdint.h>

// Problem constants (fixed by setup_inputs)
#define NB 32
#define NC 128
#define NH 56
#define NW 56
#define NHW_ (NH * NW)      // 3136
#define NPIX (NB * NHW_)    // 100352
#define NO 128
#define NK 1152             // NC * 9
#define ROWPAIRS (NH / 2)   // 28

typedef unsigned long long u64;

// ---------------------------------------------------------------------------
// K1: sign(x + bias0) packed into 128-bit-per-pixel bitplanes.
// ---------------------------------------------------------------------------
__global__ __launch_bounds__(256) void pack_act(const float* __restrict__ x,
                                                const float* __restrict__ bias0,
                                                u64* __restrict__ packA) {
    int p = blockIdx.x * 256 + threadIdx.x;  // pixel index n*HW + h*W + w
    if (p >= NPIX) return;
    int n = p / NHW_;
    int rem = p - n * NHW_;
    const float* xb = x + (size_t)n * NC * NHW_ + rem;
    u64 w0 = 0, w1 = 0;
#pragma unroll 8
    for (int c = 0; c < 64; ++c)
        w0 |= (u64)((xb[(size_t)c * NHW_] + bias0[c]) > 0.f) << c;
#pragma unroll 8
    for (int c = 0; c < 64; ++c)
        w1 |= (u64)((xb[(size_t)(c + 64) * NHW_] + bias0[c + 64]) > 0.f) << c;
    packA[(size_t)p * 2]     = w0;
    packA[(size_t)p * 2 + 1] = w1;
}

// ---------------------------------------------------------------------------
// K2: per-output-channel weight scale (mean |w|) + sign bitplanes.
// packW[o][tap][j]: offset o*144B + tap*16B + j*8B (16B-aligned per tap).
// ---------------------------------------------------------------------------
__global__ __launch_bounds__(64) void pack_wgt(const float* __restrict__ w,
                                               u64* __restrict__ packW,
                                               float* __restrict__ scaleW) {
    int o = blockIdx.x;
    int t = threadIdx.x;  // 64 threads
    const float* wo = w + (size_t)o * NK;
    float s = 0.f;
    for (int i = t; i < NK; i += 64) s += fabsf(wo[i]);
    for (int off = 32; off; off >>= 1) s += __shfl_down(s, off);
    if (t == 0) scaleW[o] = s / (float)NK;
    if (t < 18) {
        int tap = t >> 1;
        int j   = t & 1;
        u64 bits = 0;
        for (int cc = 0; cc < 64; ++cc) {
            int c = j * 64 + cc;
            bits |= (u64)(wo[c * 9 + tap] > 0.f) << cc;
        }
        packW[((size_t)o * 9 + tap) * 2 + j] = bits;
    }
}

// ---------------------------------------------------------------------------
// K3: binary conv, 2 output rows per block. No shuffles, no atomics.
// Block = (n, row-pair); 4 waves x 32 channels; lanes 0..55 = w.
// ---------------------------------------------------------------------------
__global__ __launch_bounds__(256) void conv_bin(const u64* __restrict__ packA,
                                                const u64* __restrict__ packW,
                                                short* __restrict__ yI) {
    __shared__ u64 lw[NO * 18];  // 18 KB
    for (int i = threadIdx.x; i < NO * 18; i += 256) lw[i] = packW[i];

    int bid = blockIdx.x;  // n * ROWPAIRS + hp
    int n = bid / ROWPAIRS, hp = bid - n * ROWPAIRS;
    int h0 = hp * 2;
    int wave = threadIdx.x >> 6, lane = threadIdx.x & 63;
    bool act = lane < NW;

    // 4 input rows (h0-1..h0+2) x 3 cols (w-1..w+1), 2 words each -> 48 VGPRs
    u64 a[4][3][2];
    bool rv[4], cv[3];
#pragma unroll
    for (int r = 0; r < 4; ++r) {
        int hi = h0 - 1 + r;
        rv[r] = (hi >= 0) && (hi < NH);
    }
    cv[0] = act && (lane >= 1);
    cv[1] = act;
    cv[2] = act && (lane + 1 < NW);
#pragma unroll
    for (int r = 0; r < 4; ++r) {
        int hi = h0 - 1 + r;
        int hc = hi < 0 ? 0 : (hi >= NH ? NH - 1 : hi);
#pragma unroll
        for (int c = 0; c < 3; ++c) {
            int wi = lane - 1 + c;
            int wc = wi < 0 ? 0 : (wi >= NW ? NW - 1 : wi);
            size_t idx = ((size_t)n * NHW_ + (size_t)hc * NW + wc) * 2;
            ulonglong2 q = *reinterpret_cast<const ulonglong2*>(packA + idx);
            bool v = rv[r] && cv[c];
            a[r][c][0] = v ? q.x : 0;
            a[r][c][1] = v ? q.y : 0;
        }
    }
    __syncthreads();

    short* yrow = yI + (size_t)n * NO * NHW_ + (size_t)h0 * NW + lane;

    for (int oo = 0; oo < 32; ++oo) {
        int o = (wave << 5) + oo;
        const u64* wp = &lw[o * 18];
        int dot0 = 0, dot1 = 0;
#pragma unroll
        for (int kh = 0; kh < 3; ++kh) {
#pragma unroll
            for (int kw = 0; kw < 3; ++kw) {
                int t = kh * 3 + kw;
                u64 w0 = wp[2 * t], w1 = wp[2 * t + 1];
                int pc0 = __popcll(a[kh][kw][0] ^ w0) + __popcll(a[kh][kw][1] ^ w1);
                int pc1 = __popcll(a[kh + 1][kw][0] ^ w0) + __popcll(a[kh + 1][kw][1] ^ w1);
                dot0 += (rv[kh] && cv[kw]) ? (NC - 2 * pc0) : 0;
                dot1 += (rv[kh + 1] && cv[kw]) ? (NC - 2 * pc1) : 0;
            }
        }
        if (act) {
            yrow[(size_t)o * NHW_]      = (short)dot0;
            yrow[(size_t)o * NHW_ + NW] = (short)dot1;
        }
    }
}

// ---------------------------------------------------------------------------
// K3b: per-channel sum/sumsq from yI. Grid = NO*4; block b -> (o=b>>2, q=b&3)
// covers n in [8q, 8q+8). LDS tree reduce, no atomics, exact integers.
// ---------------------------------------------------------------------------
__global__ __launch_bounds__(256) void stats_y(const short* __restrict__ yI,
                                               int* __restrict__ sumP,
                                               u64* __restrict__ sqP) {
    int b = blockIdx.x;
    int o = b >> 2, q = b & 3;
    long long s = 0, sq = 0;
    // 8 planes x 392 int4(=8 shorts) vectors = 3136 vectors
    for (int v = threadIdx.x; v < 3136; v += 256) {
        int nl = v / 392, off = v - nl * 392;
        int n = q * 8 + nl;
        const int4 pv = *reinterpret_cast<const int4*>(
            yI + ((size_t)n * NO + o) * NHW_ + (size_t)off * 8);
        int qs[4] = {pv.x, pv.y, pv.z, pv.w};
#pragma unroll
        for (int j = 0; j < 4; ++j) {
            int lo = (int)(short)(qs[j] & 0xffff);
            int hi = (int)(qs[j] >> 16);
            s += lo + hi;
            sq += (long long)(lo * lo + hi * hi);
        }
    }
    __shared__ long long ls[256];
    __shared__ long long lq[256];
    int tid = threadIdx.x;
    ls[tid] = s; lq[tid] = sq;
    __syncthreads();
    for (int st = 128; st; st >>= 1) {
        if (tid < st) { ls[tid] += ls[tid + st]; lq[tid] += lq[tid + st]; }
        __syncthreads();
    }
    if (tid == 0) {
        sumP[o * 4 + q] = (int)ls[0];
        sqP[o * 4 + q]  = (u64)lq[0];
    }
}

// ---------------------------------------------------------------------------
// K4: fold scale + BN + bias1 into per-channel affine (sums nparts partials).
// ---------------------------------------------------------------------------
__global__ __launch_bounds__(128) void bn_coef(const int* __restrict__ sumP,
                                               const u64* __restrict__ sqP,
                                               const float* __restrict__ scaleW,
                                               const float* __restrict__ gamma,
                                               const float* __restrict__ beta,
                                               const float* __restrict__ bias1,
                                               float* __restrict__ coefA,
                                               float* __restrict__ coefB,
                                               int nparts) {
    int o = threadIdx.x;
    long long si = 0; u64 qi = 0;
    for (int k = 0; k < nparts; ++k) {
        si += sumP[o * nparts + k];
        qi += sqP[o * nparts + k];
    }
    double cnt = (double)NPIX;
    double mean = (double)si / cnt;
    double var = (double)qi / cnt - mean * mean;
    if (var < 0.0) var = 0.0;
    float sc = scaleW[o];
    float rs = rsqrtf((float)((double)sc * (double)sc * var) + 1e-5f);
    float g = gamma[o];
    float a = sc * g * rs;
    float b = beta[o] - (float)((double)sc * mean) * g * rs;
    coefA[o] = a;
    coefB[o] = b + bias1[o];
}

// ---------------------------------------------------------------------------
// K5a (store path): elementwise epilogue, 8 elems/thread vectorized.
// out = prelu(coefA*y + coefB + x) + bias2
// ---------------------------------------------------------------------------
__global__ __launch_bounds__(256) void final_store(const short* __restrict__ yI,
                                                   const float* __restrict__ x,
                                                   const float* __restrict__ coefA,
                                                   const float* __restrict__ coefB,
                                                   const float* __restrict__ alpha,
                                                   const float* __restrict__ bias2,
                                                   float* __restrict__ out) {
    const size_t ngroups = (size_t)NB * NO * NHW_ / 8;
    for (size_t g = (size_t)blockIdx.x * blockDim.x + threadIdx.x; g < ngroups;
         g += (size_t)gridDim.x * blockDim.x) {
        size_t i = g * 8;
        int o = (int)((i / NHW_) % NO);
        float a = coefA[o], bb = coefB[o], al = alpha[o], b2 = bias2[o];
        int4 yv = *reinterpret_cast<const int4*>(yI + i);
        float4 x0 = *reinterpret_cast<const float4*>(x + i);
        float4 x1 = *reinterpret_cast<const float4*>(x + i + 4);
        int q[4] = {yv.x, yv.y, yv.z, yv.w};
        float xs[8] = {x0.x, x0.y, x0.z, x0.w, x1.x, x1.y, x1.z, x1.w};
        float r[8];
#pragma unroll
        for (int j = 0; j < 4; ++j) {
            float lo = (float)(short)(q[j] & 0xffff);
            float hi = (float)(q[j] >> 16);
            float t0 = fmaf(a, lo, bb) + xs[2 * j];
            float t1 = fmaf(a, hi, bb) + xs[2 * j + 1];
            t0 = t0 >= 0.f ? t0 : al * t0;
            t1 = t1 >= 0.f ? t1 : al * t1;
            r[2 * j]     = t0 + b2;
            r[2 * j + 1] = t1 + b2;
        }
        float4 o0 = {r[0], r[1], r[2], r[3]};
        float4 o1 = {r[4], r[5], r[6], r[7]};
        *reinterpret_cast<float4*>(out + i)     = o0;
        *reinterpret_cast<float4*>(out + i + 4) = o1;
    }
}

// ---------------------------------------------------------------------------
// Fallback path (tiny-ws): old atomic-based stats conv + recompute epilogue.
// Only used if ws can't hold yI. Slow but correct.
// ---------------------------------------------------------------------------
__device__ inline void load_nbhd(const u64* __restrict__ packA, int n, int h,
                                 int wcol, bool act, u64 a[9][2], unsigned* vmask) {
    unsigned m = 0;
#pragma unroll
    for (int kh = 0; kh < 3; ++kh) {
        int hi = h + kh - 1;
        bool vh = (hi >= 0) && (hi < NH);
#pragma unroll
        for (int kw = 0; kw < 3; ++kw) {
            int wi = wcol + kw - 1;
            int t = kh * 3 + kw;
            bool v = act && vh && (wi >= 0) && (wi < NW);
            int hc = hi < 0 ? 0 : (hi >= NH ? NH - 1 : hi);
            int wc = wi < 0 ? 0 : (wi >= NW ? NW - 1 : wi);
            size_t idx = ((size_t)n * NHW_ + (size_t)hc * NW + wc) * 2;
            u64 q0 = packA[idx], q1 = packA[idx + 1];
            a[t][0] = v ? q0 : 0;
            a[t][1] = v ? q1 : 0;
            m |= (unsigned)v << t;
        }
    }
    *vmask = m;
}

__global__ __launch_bounds__(256) void conv_stats_atomic(const u64* __restrict__ packA,
                                                         const u64* __restrict__ packW,
                                                         int* __restrict__ sumI,
                                                         u64* __restrict__ sumsqI) {
    __shared__ u64 lw[NO * 18];
    for (int i = threadIdx.x; i < NO * 18; i += 256) lw[i] = packW[i];
    int nh = blockIdx.x;
    int n = nh / NH, h = nh - n * NH;
    int wave = threadIdx.x >> 6, lane = threadIdx.x & 63;
    bool act = lane < NW;
    u64 a[9][2]; unsigned vm;
    load_nbhd(packA, n, h, lane, act, a, &vm);
    __syncthreads();
    for (int oo = 0; oo < 32; ++oo) {
        int o = (wave << 5) + oo;
        int dot = 0;
#pragma unroll
        for (int t = 0; t < 9; ++t) {
            int pc = __popcll(a[t][0] ^ lw[(o * 9 + t) * 2]) +
                     __popcll(a[t][1] ^ lw[(o * 9 + t) * 2 + 1]);
            dot += ((vm >> t) & 1) ? (NC - 2 * pc) : 0;
        }
        int s = dot, sq = dot * dot;
        for (int off = 32; off; off >>= 1) {
            s  += __shfl_down(s, off);
            sq += __shfl_down(sq, off);
        }
        if (lane == 0) {
            atomicAdd(&sumI[o], s);
            atomicAdd(&sumsqI[o], (u64)(unsigned)sq);
        }
    }
}

__global__ __launch_bounds__(256) void final_recompute(const u64* __restrict__ packA,
                                                       const u64* __restrict__ packW,
                                                       const float* __restrict__ coefA,
                                                       const float* __restrict__ coefB,
                                                       const float* __restrict__ alpha,
                                                       const float* __restrict__ bias2,
                                                       const float* __restrict__ x,
                                                       float* __restrict__ out) {
    __shared__ u64 lw[NO * 18];
    for (int i = threadIdx.x; i < NO * 18; i += 256) lw[i] = packW[i];
    int nh = blockIdx.x;
    int n = nh / NH, h = nh - n * NH;
    int wave = threadIdx.x >> 6, lane = threadIdx.x & 63;
    bool act = lane < NW;
    u64 a[9][2]; unsigned vm;
    load_nbhd(packA, n, h, lane, act, a, &vm);
    __syncthreads();
    for (int oo = 0; oo < 32; ++oo) {
        int o = (wave << 5) + oo;
        int dot = 0;
#pragma unroll
        for (int t = 0; t < 9; ++t) {
            int pc = __popcll(a[t][0] ^ lw[(o * 9 + t) * 2]) +
                     __popcll(a[t][1] ^ lw[(o * 9 + t) * 2 + 1]);
            dot += ((vm >> t) & 1) ? (NC - 2 * pc) : 0;
        }
        if (act) {
            size_t idx = ((size_t)n * NO + o) * NHW_ + (size_t)h * NW + lane;
            float t = fmaf(coefA[o], (float)dot, coefB[o]) + x[idx];
            t = t >= 0.f ? t : alpha[o] * t;
            out[idx] = t + bias2[o];
        }
    }
}

// ---------------------------------------------------------------------------
// Workspace layout (bytes):
//   0        packA   (NB*HW*2 u64)      1,605,632
//   1605632  packW   (128*18 u64)          18,432
//   1624064  scaleW  (128 f32)                512
//   1624576  sumP    (512 i32)              2,048
//   1626624  sqP     (512 u64)              4,096
//   1630720  coefA   (128 f32)                512
//   1631232  coefB   (128 f32)                512
//   1631744  yI      (int16)           25,690,112   (store path)
// ---------------------------------------------------------------------------
extern "C" void kernel_launch(void* const* d_in, const int* in_sizes, int n_in,
                              void* d_out, int out_size, void* d_ws, size_t ws_size,
                              hipStream_t stream) {
    (void)in_sizes; (void)n_in; (void)out_size;
    const float* x     = (const float*)d_in[0];
    const float* bias0 = (const float*)d_in[1];
    const float* w     = (const float*)d_in[2];
    const float* gamma = (const float*)d_in[3];
    const float* beta  = (const float*)d_in[4];
    const float* bias1 = (const float*)d_in[5];
    const float* alpha = (const float*)d_in[6];
    const float* bias2 = (const float*)d_in[7];
    float* out = (float*)d_out;
    char* ws = (char*)d_ws;

    u64*   packA  = (u64*)ws;
    u64*   packW  = (u64*)(ws + 1605632);
    float* scaleW = (float*)(ws + 1624064);
    int*   sumP   = (int*)(ws + 1624576);
    u64*   sqP    = (u64*)(ws + 1626624);
    float* coefA  = (float*)(ws + 1630720);
    float* coefB  = (float*)(ws + 1631232);
    short* yI     = (short*)(ws + 1631744);
    bool store = ws_size >= (size_t)1631744 + (size_t)NB * NO * NHW_ * 2;

    pack_act<<<NPIX / 256, 256, 0, stream>>>(x, bias0, packA);
    pack_wgt<<<NO, 64, 0, stream>>>(w, packW, scaleW);

    if (store) {
        conv_bin<<<NB * ROWPAIRS, 256, 0, stream>>>(packA, packW, yI);
        stats_y<<<NO * 4, 256, 0, stream>>>(yI, sumP, sqP);
        bn_coef<<<1, NO, 0, stream>>>(sumP, sqP, scaleW, gamma, beta, bias1, coefA, coefB, 4);
        final_store<<<2048, 256, 0, stream>>>(yI, x, coefA, coefB, alpha, bias2, out);
    } else {
        hipMemsetAsync(sumP, 0, 2048 + 4096, stream);
        conv_stats_atomic<<<NB * NH, 256, 0, stream>>>(packA, packW, sumP, sqP);
        bn_coef<<<1, NO, 0, stream>>>(sumP, sqP, scaleW, gamma, beta, bias1, coefA, coefB, 1);
        final_recompute<<<NB * NH, 256, 0, stream>>>(packA, packW, coefA, coefB, alpha, bias2, x, out);
    }
}